// Round 16
// baseline (1063.621 us; speedup 1.0000x reference)
//
#include <hip/hip_runtime.h>
#include <math.h>

#define TT 12
#define FF 32
#define HH 64
#define OO 8
#define GG 256   // 4*HH
#define NF 4     // NUM_FUTURE
#define BRS 32   // nodes per lstm block (2 row-tiles of 16)

typedef __bf16 bf16x8 __attribute__((ext_vector_type(8)));
typedef float  f32x4  __attribute__((ext_vector_type(4)));

__device__ __forceinline__ float sigmoidf_(float x){ return 1.f/(1.f+expf(-x)); }
__device__ __forceinline__ unsigned short f2bf(float f){   // round-to-nearest-even
  unsigned int u = __float_as_uint(f);
  u += 0x7FFFu + ((u >> 16) & 1u);
  return (unsigned short)(u >> 16);
}
__device__ __forceinline__ float bf2f(unsigned short b){
  return __uint_as_float(((unsigned int)b) << 16);
}

// ================= CSR build =================
__global__ void hist_kernel(const int* __restrict__ dst, int* __restrict__ cnt, int E){
  int e = blockIdx.x*blockDim.x + threadIdx.x;
  if (e < E) atomicAdd(&cnt[dst[e]], 1);
}

__global__ __launch_bounds__(1024) void scan_kernel(const int* __restrict__ cnt,
                                                    int* __restrict__ ptr,
                                                    float* __restrict__ invd, int N){
  __shared__ int buf[1024];
  __shared__ int carry;
  if (threadIdx.x == 0) carry = 0;
  __syncthreads();
  for (int base = 0; base < N; base += 1024){
    int i = base + threadIdx.x;
    int v = (i < N) ? cnt[i] : 0;
    buf[threadIdx.x] = v;
    __syncthreads();
    for (int off = 1; off < 1024; off <<= 1){
      int t = (threadIdx.x >= off) ? buf[threadIdx.x - off] : 0;
      __syncthreads();
      buf[threadIdx.x] += t;
      __syncthreads();
    }
    int incl = buf[threadIdx.x];
    if (i < N){
      ptr[i] = carry + incl - v;
      invd[i] = 1.f / fmaxf((float)v, 1.f);
    }
    __syncthreads();
    if (threadIdx.x == 1023){
      carry += incl;
      if (base + 1024 >= N) ptr[N] = carry;
    }
    __syncthreads();
  }
}

__global__ void fill_kernel(const int* __restrict__ src, const int* __restrict__ dst,
                            const float* __restrict__ ew, const int* __restrict__ ptr,
                            int* __restrict__ fill, int2* __restrict__ csr_sw, int E){
  int e = blockIdx.x*blockDim.x + threadIdx.x;
  if (e >= E) return;
  int d = dst[e];
  int pos = ptr[d] + atomicAdd(&fill[d], 1);
  int2 m; m.x = src[e]; m.y = __float_as_int(ew[e]);
  csr_sw[pos] = m;
}

// ====== fp32 [t][n][f] -> bf16 node-major [(n*TT+t)*FF+f] ======
__global__ void xpose_conv(const float* __restrict__ in, unsigned short* __restrict__ out,
                           int N){
  int idx = blockIdx.x*blockDim.x + threadIdx.x;
  if (idx >= TT*N*FF) return;
  int f = idx & (FF-1);
  int rem = idx >> 5;          // n*TT + t
  int t = rem % TT, n = rem / TT;
  out[idx] = f2bf(in[(size_t)t*N*FF + (size_t)n*FF + f]);
}

// ====== MFMA B-fragment weight packing (bf16), LSTM K=256 ======
__global__ void pack_wfrag(const float* __restrict__ Wr, const float* __restrict__ Wroot,
                           unsigned short* __restrict__ Wfrag){
  int idx = blockIdx.x*256 + threadIdx.x;
  if (idx >= 16*8*64*8) return;
  int e  = idx & 7;
  int l  = (idx >> 3) & 63;
  int ks = (idx >> 9) & 7;
  int jt = idx >> 12;
  int k = ks*32 + (l>>4)*8 + e;
  int j = jt*16 + (l&15);
  float v = (k < 128) ? Wr[(size_t)k*GG + j] : Wroot[(size_t)(k-128)*GG + j];
  Wfrag[idx] = f2bf(v);
}

// ====== MFMA B-fragment packing, SAGE K=64 ======
__global__ void pack_sfrag(const float* __restrict__ Wr, const float* __restrict__ Wroot,
                           unsigned short* __restrict__ Sfrag){
  int idx = blockIdx.x*256 + threadIdx.x;
  if (idx >= 4*2*64*8) return;
  int e  = idx & 7;
  int l  = (idx >> 3) & 63;
  int ks = (idx >> 9) & 1;
  int jt = idx >> 10;
  int k = ks*32 + (l>>4)*8 + e;   // 0..63
  int j = jt*16 + (l&15);
  float v = (k < 32) ? Wr[(size_t)k*HH + j] : Wroot[(size_t)(k-32)*HH + j];
  Sfrag[idx] = f2bf(v);
}

// ========== SAGE aggregation, node-major ==========
__global__ __launch_bounds__(256) void sage_gather(
    const unsigned short* __restrict__ xb, const int* __restrict__ ptr,
    const int2* __restrict__ csr_sw,
    const float* __restrict__ invd, unsigned short* __restrict__ aggb, int N){
  int wave = threadIdx.x >> 6, lane = threadIdx.x & 63;
  int f = lane & 31, tp = lane >> 5;
  int n = blockIdx.x*4 + wave;
  if (n >= N) return;
  int beg = ptr[n], end = ptr[n+1];
  float id = invd[n];
  float acc[TT/2];
  #pragma unroll
  for (int th = 0; th < TT/2; ++th) acc[th] = 0.f;
  int e = beg;
  for (; e+2 <= end; e += 2){
    int2 m0 = csr_sw[e], m1 = csr_sw[e+1];
    const unsigned short* p0 = xb + (size_t)m0.x*TT*FF + tp*FF + f;
    const unsigned short* p1 = xb + (size_t)m1.x*TT*FF + tp*FF + f;
    float w0 = __int_as_float(m0.y), w1 = __int_as_float(m1.y);
    #pragma unroll
    for (int th = 0; th < TT/2; ++th)
      acc[th] += bf2f(p0[2*th*FF])*w0 + bf2f(p1[2*th*FF])*w1;
  }
  for (; e < end; ++e){
    int2 m = csr_sw[e];
    const unsigned short* p = xb + (size_t)m.x*TT*FF + tp*FF + f;
    float wv = __int_as_float(m.y);
    #pragma unroll
    for (int th = 0; th < TT/2; ++th)
      acc[th] += bf2f(p[2*th*FF])*wv;
  }
  #pragma unroll
  for (int th = 0; th < TT/2; ++th)
    aggb[(size_t)n*TT*FF + (2*th+tp)*FF + f] = f2bf(acc[th] * id);  // pre-normalized
}

// ====== SAGE linear via MFMA over linear rows ro = n*TT+t ======
__global__ __launch_bounds__(256) void sage_mfma(
    const unsigned short* __restrict__ aggb, const unsigned short* __restrict__ xb,
    const unsigned short* __restrict__ Sfrag, const float* __restrict__ bias,
    float* __restrict__ emb, unsigned short* __restrict__ xrb, int N, int Mrows){
  int tid = threadIdx.x, wave = tid >> 6, lane = tid & 63;
  int rbase = blockIdx.x*64 + wave*16;
  if (rbase >= Mrows) return;
  int l15 = lane & 15, l4 = lane >> 4;
  int row = rbase + l15;
  bf16x8 af0 = *(const bf16x8*)&aggb[(size_t)row*FF + l4*8];   // k 0..31
  bf16x8 af1 = *(const bf16x8*)&xb  [(size_t)row*FF + l4*8];   // k 32..63
  f32x4 acc[4];
  #pragma unroll
  for (int jt = 0; jt < 4; ++jt){
    float bv = bias[jt*16 + l15];
    acc[jt][0]=bv; acc[jt][1]=bv; acc[jt][2]=bv; acc[jt][3]=bv;
  }
  #pragma unroll
  for (int jt = 0; jt < 4; ++jt){
    bf16x8 b0 = *(const bf16x8*)&Sfrag[(size_t)(((jt*2+0)*64) + lane) * 8];
    bf16x8 b1 = *(const bf16x8*)&Sfrag[(size_t)(((jt*2+1)*64) + lane) * 8];
    acc[jt] = __builtin_amdgcn_mfma_f32_16x16x32_bf16(af0, b0, acc[jt], 0, 0, 0);
    acc[jt] = __builtin_amdgcn_mfma_f32_16x16x32_bf16(af1, b1, acc[jt], 0, 0, 0);
  }
  #pragma unroll
  for (int jt = 0; jt < 4; ++jt){
    int col = jt*16 + l15;
    #pragma unroll
    for (int i = 0; i < 4; ++i){
      int ro = rbase + l4*4 + i;        // ro = n*TT + t
      int t = ro % TT, n = ro / TT;
      float v = acc[jt][i];
      emb[(size_t)t*N*HH + (size_t)n*HH + col] = v;
      xrb[(size_t)ro*HH + col] = f2bf(fmaxf(v, 0.f));
    }
  }
}

// ========== xr aggregation, node-major ==========
__global__ __launch_bounds__(256) void xr_gather(
    const unsigned short* __restrict__ xrb, const int* __restrict__ ptr,
    const int2* __restrict__ csr_sw,
    const float* __restrict__ invd, unsigned short* __restrict__ xr_aggb, int N){
  int wave = threadIdx.x >> 6, lane = threadIdx.x & 63;
  int n = blockIdx.x*4 + wave;
  if (n >= N) return;
  int beg = ptr[n], end = ptr[n+1];
  float id = invd[n];
  float acc[TT];
  #pragma unroll
  for (int t = 0; t < TT; ++t) acc[t] = 0.f;
  int e = beg;
  for (; e+2 <= end; e += 2){
    int2 m0 = csr_sw[e], m1 = csr_sw[e+1];
    const unsigned short* p0 = xrb + (size_t)m0.x*TT*HH + lane;
    const unsigned short* p1 = xrb + (size_t)m1.x*TT*HH + lane;
    float w0 = __int_as_float(m0.y), w1 = __int_as_float(m1.y);
    #pragma unroll
    for (int t = 0; t < TT; ++t)
      acc[t] += bf2f(p0[t*HH])*w0 + bf2f(p1[t*HH])*w1;
  }
  for (; e < end; ++e){
    int2 m = csr_sw[e];
    const unsigned short* p = xrb + (size_t)m.x*TT*HH + lane;
    float wv = __int_as_float(m.y);
    #pragma unroll
    for (int t = 0; t < TT; ++t)
      acc[t] += bf2f(p[t*HH])*wv;
  }
  #pragma unroll
  for (int t = 0; t < TT; ++t)
    xr_aggb[(size_t)n*TT*HH + t*HH + lane] = f2bf(acc[t] * id);  // pre-normalized
}

// ====== fused step, BRS=32 nodes, 1024 thr / 16 waves ======
// Phase A: wave w gathers rows 2w,2w+1. Phase B: wave w owns col-tile jt=w for
// BOTH row-tiles (B-fragment regs reused; block Wfrag read halved per node).
// Phase C: wave w updates rows 2w,2w+1.
__global__ __launch_bounds__(1024) void lstm_mfma(
    const unsigned short* __restrict__ xrb_t, const unsigned short* __restrict__ xraggb_t,
    const unsigned short* __restrict__ h_prev, unsigned short* __restrict__ h_next,
    float* __restrict__ c, const float* __restrict__ invd,
    const int* __restrict__ ptr, const int2* __restrict__ csr_sw,
    const unsigned short* __restrict__ Wfrag, const float* __restrict__ bias,
    unsigned short* __restrict__ h2_store, int N){
  __shared__ __align__(16) unsigned short Albuf[BRS][264];  // bf16 A-tile
  __shared__ float gbuf[BRS][260];                          // fp32 gates
  int tid = threadIdx.x, wave = tid >> 6, lane = tid & 63;
  int base = blockIdx.x * BRS;

  // ---- Phase A ----
  #pragma unroll
  for (int r2 = 0; r2 < 2; ++r2){
    int r = wave*2 + r2;
    int n = base + r;
    if (n < N){
      float id = invd[n];
      int beg = ptr[n], end = ptr[n+1];
      float a0=0.f,a1=0.f,a2=0.f,a3=0.f,a4=0.f,a5=0.f,a6=0.f,a7=0.f;
      int e = beg;
      for (; e+8 <= end; e += 8){
        int2 m0=csr_sw[e+0], m1=csr_sw[e+1], m2=csr_sw[e+2], m3=csr_sw[e+3];
        int2 m4=csr_sw[e+4], m5=csr_sw[e+5], m6=csr_sw[e+6], m7=csr_sw[e+7];
        a0 += bf2f(h_prev[(size_t)m0.x*HH+lane])*__int_as_float(m0.y);
        a1 += bf2f(h_prev[(size_t)m1.x*HH+lane])*__int_as_float(m1.y);
        a2 += bf2f(h_prev[(size_t)m2.x*HH+lane])*__int_as_float(m2.y);
        a3 += bf2f(h_prev[(size_t)m3.x*HH+lane])*__int_as_float(m3.y);
        a4 += bf2f(h_prev[(size_t)m4.x*HH+lane])*__int_as_float(m4.y);
        a5 += bf2f(h_prev[(size_t)m5.x*HH+lane])*__int_as_float(m5.y);
        a6 += bf2f(h_prev[(size_t)m6.x*HH+lane])*__int_as_float(m6.y);
        a7 += bf2f(h_prev[(size_t)m7.x*HH+lane])*__int_as_float(m7.y);
      }
      for (; e < end; ++e){
        int2 m = csr_sw[e];
        a0 += bf2f(h_prev[(size_t)m.x*HH+lane])*__int_as_float(m.y);
      }
      float hag = (((a0+a1)+(a2+a3))+((a4+a5)+(a6+a7))) * id;
      Albuf[r][    lane] = xraggb_t[(size_t)n*TT*HH + lane];
      Albuf[r][ 64+lane] = f2bf(hag);
      Albuf[r][128+lane] = xrb_t [(size_t)n*TT*HH + lane];
      Albuf[r][192+lane] = h_prev[(size_t)n*HH + lane];
    } else {
      Albuf[r][lane] = Albuf[r][64+lane] = Albuf[r][128+lane] = Albuf[r][192+lane] = 0;
    }
  }
  __syncthreads();

  // ---- Phase B: jt = wave; 2 row-tiles share each B-fragment ----
  int l15 = lane & 15, l4 = lane >> 4;
  int jt = wave;
  f32x4 acc0, acc1;
  {
    float bv = bias[jt*16 + l15];
    acc0[0]=bv; acc0[1]=bv; acc0[2]=bv; acc0[3]=bv;
    acc1 = acc0;
  }
  #pragma unroll
  for (int ks = 0; ks < 8; ++ks){
    bf16x8 bfr = *(const bf16x8*)&Wfrag[(size_t)(((jt*8 + ks)*64) + lane) * 8];
    bf16x8 af0 = *(const bf16x8*)&Albuf[l15     ][ks*32 + l4*8];
    bf16x8 af1 = *(const bf16x8*)&Albuf[16 + l15][ks*32 + l4*8];
    acc0 = __builtin_amdgcn_mfma_f32_16x16x32_bf16(af0, bfr, acc0, 0, 0, 0);
    acc1 = __builtin_amdgcn_mfma_f32_16x16x32_bf16(af1, bfr, acc1, 0, 0, 0);
  }
  // D layout: col = lane&15, row = (lane>>4)*4 + i (m89-verified)
  {
    int col = jt*16 + l15;
    #pragma unroll
    for (int i = 0; i < 4; ++i){
      gbuf[     l4*4 + i][col] = acc0[i];
      gbuf[16 + l4*4 + i][col] = acc1[i];
    }
  }
  __syncthreads();

  // ---- Phase C ----
  #pragma unroll
  for (int r2 = 0; r2 < 2; ++r2){
    int r = wave*2 + r2;
    int n = base + r;
    if (n < N){
      float gi = gbuf[r][lane], gf = gbuf[r][64+lane], gg2 = gbuf[r][128+lane], go = gbuf[r][192+lane];
      float cn = sigmoidf_(gf)*c[(size_t)n*HH+lane] + sigmoidf_(gi)*tanhf(gg2);
      float hnv = sigmoidf_(go)*tanhf(cn);
      c[(size_t)n*HH+lane] = cn;
      unsigned short hb = f2bf(hnv);
      h_next[(size_t)n*HH+lane] = hb;
      if (h2_store) h2_store[(size_t)n*HH+lane] = hb;
    }
  }
}

// ================= output head (bf16 inputs; xrb node-major) =================
__global__ void out_gemm(const unsigned short* __restrict__ xrb, const unsigned short* __restrict__ h2s,
                         const float* __restrict__ Wout, const float* __restrict__ bout,
                         float* __restrict__ out, int N){
  int idx = blockIdx.x*blockDim.x + threadIdx.x;
  if (idx >= NF*N*OO) return;
  int o = idx & (OO-1);
  int row = idx >> 3;                     // tt*N + n
  int tt = row / N, n = row % N;
  const unsigned short* xv = xrb + ((size_t)n*TT + (TT-NF) + tt)*HH;
  const unsigned short* hv = h2s + (size_t)row*HH;
  float acc = bout[o];
  #pragma unroll
  for (int k = 0; k < HH; ++k)
    acc += bf2f(xv[k])*Wout[k*OO+o] + bf2f(hv[k])*Wout[(HH+k)*OO+o];
  out[idx] = acc;
}

__global__ void copyk(const float* __restrict__ s, float* __restrict__ d, int n){
  int i = blockIdx.x*blockDim.x + threadIdx.x;
  if (i < n) d[i] = s[i];
}

extern "C" void kernel_launch(void* const* d_in, const int* in_sizes, int n_in,
                              void* d_out, int out_size, void* d_ws, size_t ws_size,
                              hipStream_t stream){
  const float* x      = (const float*)d_in[0];
  const int*   ei     = (const int*)  d_in[1];
  const float* ew     = (const float*)d_in[2];
  const float* sWr    = (const float*)d_in[3];
  const float* sWroot = (const float*)d_in[4];
  const float* sb     = (const float*)d_in[5];
  const float* l1Wr   = (const float*)d_in[6];
  const float* l1Wroot= (const float*)d_in[7];
  const float* l1b    = (const float*)d_in[8];
  const float* l2Wr   = (const float*)d_in[9];
  const float* l2Wroot= (const float*)d_in[10];
  const float* l2b    = (const float*)d_in[11];
  const float* Wout   = (const float*)d_in[12];
  const float* bout   = (const float*)d_in[13];

  const int E = in_sizes[2];
  const int N = in_sizes[0] / (TT*FF);
  const int* src = ei;
  const int* dst = ei + E;

  float* out0   = (float*)d_out;              // [4,N,8]
  float* c2out  = out0 + (size_t)NF*N*OO;     // [N,64]
  float* embout = c2out + (size_t)N*HH;       // [12,N,64]

  float* w = (float*)d_ws;
  float* cbuf   = w;  w += (size_t)N*HH;
  float* invd   = w;  w += N;
  int*   cnt    = (int*)w;  w += N;
  int*   fill   = (int*)w;  w += N;
  int*   ptr    = (int*)w;  w += (N+2);       // keep int2 array 8B-aligned
  int2*  csr_sw = (int2*)w; w += (size_t)2*E;
  unsigned short* Wf1 = (unsigned short*)w; w += (size_t)16*8*64*8/2;
  unsigned short* Wf2 = (unsigned short*)w; w += (size_t)16*8*64*8/2;
  unsigned short* Sfg = (unsigned short*)w; w += (size_t)4*2*64*8/2;
  unsigned short* xb     = (unsigned short*)w; w += (size_t)TT*N*FF/2;
  unsigned short* aggb   = (unsigned short*)w; w += (size_t)TT*N*FF/2;
  unsigned short* xrb    = (unsigned short*)w; w += (size_t)TT*N*HH/2;
  unsigned short* xraggb = (unsigned short*)w; w += (size_t)TT*N*HH/2;
  unsigned short* hA     = (unsigned short*)w; w += (size_t)N*HH/2;
  unsigned short* hB     = (unsigned short*)w; w += (size_t)N*HH/2;
  unsigned short* h2s    = (unsigned short*)w; w += (size_t)NF*N*HH/2;

  hipMemsetAsync(cnt,  0, (size_t)N*4, stream);
  hipMemsetAsync(fill, 0, (size_t)N*4, stream);
  hipMemsetAsync(hA,   0, (size_t)N*HH*2, stream);  // h0 (bf16 zero = 0)
  hipMemsetAsync(cbuf, 0, (size_t)N*HH*4, stream);  // c0

  hist_kernel<<<(E+255)/256, 256, 0, stream>>>(dst, cnt, E);
  scan_kernel<<<1, 1024, 0, stream>>>(cnt, ptr, invd, N);
  fill_kernel<<<(E+255)/256, 256, 0, stream>>>(src, dst, ew, ptr, fill, csr_sw, E);

  pack_wfrag<<<(16*8*64*8+255)/256, 256, 0, stream>>>(l1Wr, l1Wroot, Wf1);
  pack_wfrag<<<(16*8*64*8+255)/256, 256, 0, stream>>>(l2Wr, l2Wroot, Wf2);
  pack_sfrag<<<(4*2*64*8+255)/256, 256, 0, stream>>>(sWr, sWroot, Sfg);
  xpose_conv<<<((size_t)TT*N*FF+255)/256, 256, 0, stream>>>(x, xb, N);

  sage_gather<<<(N+3)/4, 256, 0, stream>>>(xb, ptr, csr_sw, invd, aggb, N);
  {
    int Mrows = TT*N;
    sage_mfma<<<(Mrows+63)/64, 256, 0, stream>>>(aggb, xb, Sfg, sb, embout, xrb, N, Mrows);
  }
  xr_gather<<<(N+3)/4, 256, 0, stream>>>(xrb, ptr, csr_sw, invd, xraggb, N);

  const int sBlocks = (N + BRS - 1) / BRS;   // 625
  unsigned short* hp = hA; unsigned short* hn = hB;
  // LSTM1
  for (int t = 0; t < TT; ++t){
    lstm_mfma<<<sBlocks, 1024, 0, stream>>>(xrb + (size_t)t*HH, xraggb + (size_t)t*HH,
                                            hp, hn, cbuf, invd, ptr, csr_sw,
                                            Wf1, l1b, nullptr, N);
    unsigned short* tmp = hp; hp = hn; hn = tmp;
  }
  // LSTM2 (continues from h1[-1], c1); h2 stored for t>=8
  for (int t = 0; t < TT; ++t){
    unsigned short* store = (t >= TT-NF) ? (h2s + (size_t)(t-(TT-NF))*N*HH) : nullptr;
    lstm_mfma<<<sBlocks, 1024, 0, stream>>>(xrb + (size_t)t*HH, xraggb + (size_t)t*HH,
                                            hp, hn, cbuf, invd, ptr, csr_sw,
                                            Wf2, l2b, store, N);
    unsigned short* tmp = hp; hp = hn; hn = tmp;
  }

  out_gemm<<<((size_t)NF*N*OO+255)/256, 256, 0, stream>>>(xrb, h2s,
                                                          Wout, bout, out0, N);
  copyk<<<((size_t)N*HH+255)/256, 256, 0, stream>>>(cbuf, c2out, N*HH);
}

// Round 17
// 960.565 us; speedup vs baseline: 1.1073x; 1.1073x over previous
//
#include <hip/hip_runtime.h>
#include <math.h>

#define TT 12
#define FF 32
#define HH 64
#define OO 8
#define GG 256   // 4*HH
#define NF 4     // NUM_FUTURE
#define BR 16    // nodes per lstm block

typedef __bf16 bf16x8 __attribute__((ext_vector_type(8)));
typedef float  f32x4  __attribute__((ext_vector_type(4)));

__device__ __forceinline__ float sigmoidf_(float x){ return 1.f/(1.f+expf(-x)); }
__device__ __forceinline__ unsigned short f2bf(float f){   // round-to-nearest-even
  unsigned int u = __float_as_uint(f);
  u += 0x7FFFu + ((u >> 16) & 1u);
  return (unsigned short)(u >> 16);
}
__device__ __forceinline__ float bf2f(unsigned short b){
  return __uint_as_float(((unsigned int)b) << 16);
}

// ================= CSR build =================
__global__ void hist_kernel(const int* __restrict__ dst, int* __restrict__ cnt, int E){
  int e = blockIdx.x*blockDim.x + threadIdx.x;
  if (e < E) atomicAdd(&cnt[dst[e]], 1);
}

// hierarchical scan: (1) per-block exclusive scan + totals
__global__ __launch_bounds__(1024) void scan_local(const int* __restrict__ cnt,
                                                   int* __restrict__ loc,
                                                   int* __restrict__ btot, int N){
  __shared__ int buf[1024];
  int i = blockIdx.x*1024 + threadIdx.x;
  int v = (i < N) ? cnt[i] : 0;
  buf[threadIdx.x] = v;
  __syncthreads();
  for (int off = 1; off < 1024; off <<= 1){
    int t = (threadIdx.x >= off) ? buf[threadIdx.x - off] : 0;
    __syncthreads();
    buf[threadIdx.x] += t;
    __syncthreads();
  }
  if (i < N) loc[i] = buf[threadIdx.x] - v;   // exclusive within block
  if (threadIdx.x == 1023) btot[blockIdx.x] = buf[1023];
}

// (2) single-wave scan of block totals (nb <= 64)
__global__ void scan_tot(const int* __restrict__ btot, int* __restrict__ boff,
                         int nb, int* __restrict__ ptrN){
  int l = threadIdx.x;
  int v = (l < nb) ? btot[l] : 0;
  int incl = v;
  for (int off = 1; off < 64; off <<= 1){
    int t = __shfl_up(incl, off);
    if (l >= off) incl += t;
  }
  if (l < nb) boff[l] = incl - v;
  if (l == nb-1) *ptrN = incl;
}

// (3) add block offsets; emit ptr and invd
__global__ __launch_bounds__(1024) void scan_fix(const int* __restrict__ loc,
                                                 const int* __restrict__ boff,
                                                 const int* __restrict__ cnt,
                                                 int* __restrict__ ptr,
                                                 float* __restrict__ invd, int N){
  int i = blockIdx.x*1024 + threadIdx.x;
  if (i >= N) return;
  ptr[i]  = loc[i] + boff[blockIdx.x];
  invd[i] = 1.f / fmaxf((float)cnt[i], 1.f);
}

__global__ void fill_kernel(const int* __restrict__ src, const int* __restrict__ dst,
                            const float* __restrict__ ew, const int* __restrict__ ptr,
                            int* __restrict__ fill, int2* __restrict__ csr_sw, int E){
  int e = blockIdx.x*blockDim.x + threadIdx.x;
  if (e >= E) return;
  int d = dst[e];
  int pos = ptr[d] + atomicAdd(&fill[d], 1);
  int2 m; m.x = src[e]; m.y = __float_as_int(ew[e]);
  csr_sw[pos] = m;
}

// ====== fp32 [t][n][f] -> bf16 node-major [(n*TT+t)*FF+f] ======
__global__ void xpose_conv(const float* __restrict__ in, unsigned short* __restrict__ out,
                           int N){
  int idx = blockIdx.x*blockDim.x + threadIdx.x;
  if (idx >= TT*N*FF) return;
  int f = idx & (FF-1);
  int rem = idx >> 5;          // n*TT + t
  int t = rem % TT, n = rem / TT;
  out[idx] = f2bf(in[(size_t)t*N*FF + (size_t)n*FF + f]);
}

// ====== MFMA B-fragment weight packing (bf16), LSTM K=256 ======
__global__ void pack_wfrag(const float* __restrict__ Wr, const float* __restrict__ Wroot,
                           unsigned short* __restrict__ Wfrag){
  int idx = blockIdx.x*256 + threadIdx.x;
  if (idx >= 16*8*64*8) return;
  int e  = idx & 7;
  int l  = (idx >> 3) & 63;
  int ks = (idx >> 9) & 7;
  int jt = idx >> 12;
  int k = ks*32 + (l>>4)*8 + e;
  int j = jt*16 + (l&15);
  float v = (k < 128) ? Wr[(size_t)k*GG + j] : Wroot[(size_t)(k-128)*GG + j];
  Wfrag[idx] = f2bf(v);
}

// ====== MFMA B-fragment packing, SAGE K=64 ======
__global__ void pack_sfrag(const float* __restrict__ Wr, const float* __restrict__ Wroot,
                           unsigned short* __restrict__ Sfrag){
  int idx = blockIdx.x*256 + threadIdx.x;
  if (idx >= 4*2*64*8) return;
  int e  = idx & 7;
  int l  = (idx >> 3) & 63;
  int ks = (idx >> 9) & 1;
  int jt = idx >> 10;
  int k = ks*32 + (l>>4)*8 + e;   // 0..63
  int j = jt*16 + (l&15);
  float v = (k < 32) ? Wr[(size_t)k*HH + j] : Wroot[(size_t)(k-32)*HH + j];
  Sfrag[idx] = f2bf(v);
}

// ========== SAGE aggregation, node-major ==========
__global__ __launch_bounds__(256) void sage_gather(
    const unsigned short* __restrict__ xb, const int* __restrict__ ptr,
    const int2* __restrict__ csr_sw,
    const float* __restrict__ invd, unsigned short* __restrict__ aggb, int N){
  int wave = threadIdx.x >> 6, lane = threadIdx.x & 63;
  int f = lane & 31, tp = lane >> 5;
  int n = blockIdx.x*4 + wave;
  if (n >= N) return;
  int beg = ptr[n], end = ptr[n+1];
  float id = invd[n];
  float acc[TT/2];
  #pragma unroll
  for (int th = 0; th < TT/2; ++th) acc[th] = 0.f;
  int e = beg;
  for (; e+2 <= end; e += 2){
    int2 m0 = csr_sw[e], m1 = csr_sw[e+1];
    const unsigned short* p0 = xb + (size_t)m0.x*TT*FF + tp*FF + f;
    const unsigned short* p1 = xb + (size_t)m1.x*TT*FF + tp*FF + f;
    float w0 = __int_as_float(m0.y), w1 = __int_as_float(m1.y);
    #pragma unroll
    for (int th = 0; th < TT/2; ++th)
      acc[th] += bf2f(p0[2*th*FF])*w0 + bf2f(p1[2*th*FF])*w1;
  }
  for (; e < end; ++e){
    int2 m = csr_sw[e];
    const unsigned short* p = xb + (size_t)m.x*TT*FF + tp*FF + f;
    float wv = __int_as_float(m.y);
    #pragma unroll
    for (int th = 0; th < TT/2; ++th)
      acc[th] += bf2f(p[2*th*FF])*wv;
  }
  #pragma unroll
  for (int th = 0; th < TT/2; ++th)
    aggb[(size_t)n*TT*FF + (2*th+tp)*FF + f] = f2bf(acc[th] * id);  // pre-normalized
}

// ====== SAGE linear via MFMA over linear rows ro = n*TT+t ======
__global__ __launch_bounds__(256) void sage_mfma(
    const unsigned short* __restrict__ aggb, const unsigned short* __restrict__ xb,
    const unsigned short* __restrict__ Sfrag, const float* __restrict__ bias,
    float* __restrict__ emb, unsigned short* __restrict__ xrb, int N, int Mrows){
  int tid = threadIdx.x, wave = tid >> 6, lane = tid & 63;
  int rbase = blockIdx.x*64 + wave*16;
  if (rbase >= Mrows) return;
  int l15 = lane & 15, l4 = lane >> 4;
  int row = rbase + l15;
  bf16x8 af0 = *(const bf16x8*)&aggb[(size_t)row*FF + l4*8];   // k 0..31
  bf16x8 af1 = *(const bf16x8*)&xb  [(size_t)row*FF + l4*8];   // k 32..63
  f32x4 acc[4];
  #pragma unroll
  for (int jt = 0; jt < 4; ++jt){
    float bv = bias[jt*16 + l15];
    acc[jt][0]=bv; acc[jt][1]=bv; acc[jt][2]=bv; acc[jt][3]=bv;
  }
  #pragma unroll
  for (int jt = 0; jt < 4; ++jt){
    bf16x8 b0 = *(const bf16x8*)&Sfrag[(size_t)(((jt*2+0)*64) + lane) * 8];
    bf16x8 b1 = *(const bf16x8*)&Sfrag[(size_t)(((jt*2+1)*64) + lane) * 8];
    acc[jt] = __builtin_amdgcn_mfma_f32_16x16x32_bf16(af0, b0, acc[jt], 0, 0, 0);
    acc[jt] = __builtin_amdgcn_mfma_f32_16x16x32_bf16(af1, b1, acc[jt], 0, 0, 0);
  }
  #pragma unroll
  for (int jt = 0; jt < 4; ++jt){
    int col = jt*16 + l15;
    #pragma unroll
    for (int i = 0; i < 4; ++i){
      int ro = rbase + l4*4 + i;        // ro = n*TT + t
      int t = ro % TT, n = ro / TT;
      float v = acc[jt][i];
      emb[(size_t)t*N*HH + (size_t)n*HH + col] = v;
      xrb[(size_t)ro*HH + col] = f2bf(fmaxf(v, 0.f));
    }
  }
}

// ========== xr aggregation, node-major ==========
__global__ __launch_bounds__(256) void xr_gather(
    const unsigned short* __restrict__ xrb, const int* __restrict__ ptr,
    const int2* __restrict__ csr_sw,
    const float* __restrict__ invd, unsigned short* __restrict__ xr_aggb, int N){
  int wave = threadIdx.x >> 6, lane = threadIdx.x & 63;
  int n = blockIdx.x*4 + wave;
  if (n >= N) return;
  int beg = ptr[n], end = ptr[n+1];
  float id = invd[n];
  float acc[TT];
  #pragma unroll
  for (int t = 0; t < TT; ++t) acc[t] = 0.f;
  int e = beg;
  for (; e+2 <= end; e += 2){
    int2 m0 = csr_sw[e], m1 = csr_sw[e+1];
    const unsigned short* p0 = xrb + (size_t)m0.x*TT*HH + lane;
    const unsigned short* p1 = xrb + (size_t)m1.x*TT*HH + lane;
    float w0 = __int_as_float(m0.y), w1 = __int_as_float(m1.y);
    #pragma unroll
    for (int t = 0; t < TT; ++t)
      acc[t] += bf2f(p0[t*HH])*w0 + bf2f(p1[t*HH])*w1;
  }
  for (; e < end; ++e){
    int2 m = csr_sw[e];
    const unsigned short* p = xrb + (size_t)m.x*TT*HH + lane;
    float wv = __int_as_float(m.y);
    #pragma unroll
    for (int t = 0; t < TT; ++t)
      acc[t] += bf2f(p[t*HH])*wv;
  }
  #pragma unroll
  for (int t = 0; t < TT; ++t)
    xr_aggb[(size_t)n*TT*HH + t*HH + lane] = f2bf(acc[t] * id);  // pre-normalized
}

// ====== fused step, BR=16 nodes, 1024 thr / 16 waves (R14-verified) ======
// wave w: Phase A row w; Phase B col-tile jt=w (8 MFMAs); Phase C row w.
// skip_h: h_prev is all-zero (LSTM1 step 0) -> skip the gather entirely.
__global__ __launch_bounds__(1024) void lstm_mfma(
    const unsigned short* __restrict__ xrb_t, const unsigned short* __restrict__ xraggb_t,
    const unsigned short* __restrict__ h_prev, unsigned short* __restrict__ h_next,
    float* __restrict__ c, const float* __restrict__ invd,
    const int* __restrict__ ptr, const int2* __restrict__ csr_sw,
    const unsigned short* __restrict__ Wfrag, const float* __restrict__ bias,
    unsigned short* __restrict__ h2_store, int N, int skip_h){
  __shared__ __align__(16) unsigned short Albuf[BR][264];
  __shared__ float gbuf[BR][260];
  int tid = threadIdx.x, wave = tid >> 6, lane = tid & 63;
  int base = blockIdx.x * BR;
  int n = base + wave;

  if (n < N){
    if (skip_h){
      Albuf[wave][    lane] = xraggb_t[(size_t)n*TT*HH + lane];
      Albuf[wave][ 64+lane] = 0;
      Albuf[wave][128+lane] = xrb_t [(size_t)n*TT*HH + lane];
      Albuf[wave][192+lane] = 0;
    } else {
      float id = invd[n];
      int beg = ptr[n], end = ptr[n+1];
      float a0=0.f,a1=0.f,a2=0.f,a3=0.f,a4=0.f,a5=0.f,a6=0.f,a7=0.f;
      int e = beg;
      for (; e+8 <= end; e += 8){
        int2 m0=csr_sw[e+0], m1=csr_sw[e+1], m2=csr_sw[e+2], m3=csr_sw[e+3];
        int2 m4=csr_sw[e+4], m5=csr_sw[e+5], m6=csr_sw[e+6], m7=csr_sw[e+7];
        a0 += bf2f(h_prev[(size_t)m0.x*HH+lane])*__int_as_float(m0.y);
        a1 += bf2f(h_prev[(size_t)m1.x*HH+lane])*__int_as_float(m1.y);
        a2 += bf2f(h_prev[(size_t)m2.x*HH+lane])*__int_as_float(m2.y);
        a3 += bf2f(h_prev[(size_t)m3.x*HH+lane])*__int_as_float(m3.y);
        a4 += bf2f(h_prev[(size_t)m4.x*HH+lane])*__int_as_float(m4.y);
        a5 += bf2f(h_prev[(size_t)m5.x*HH+lane])*__int_as_float(m5.y);
        a6 += bf2f(h_prev[(size_t)m6.x*HH+lane])*__int_as_float(m6.y);
        a7 += bf2f(h_prev[(size_t)m7.x*HH+lane])*__int_as_float(m7.y);
      }
      for (; e < end; ++e){
        int2 m = csr_sw[e];
        a0 += bf2f(h_prev[(size_t)m.x*HH+lane])*__int_as_float(m.y);
      }
      float hag = (((a0+a1)+(a2+a3))+((a4+a5)+(a6+a7))) * id;
      Albuf[wave][    lane] = xraggb_t[(size_t)n*TT*HH + lane];
      Albuf[wave][ 64+lane] = f2bf(hag);
      Albuf[wave][128+lane] = xrb_t [(size_t)n*TT*HH + lane];
      Albuf[wave][192+lane] = h_prev[(size_t)n*HH + lane];
    }
  } else {
    Albuf[wave][lane] = Albuf[wave][64+lane] = Albuf[wave][128+lane] = Albuf[wave][192+lane] = 0;
  }
  __syncthreads();

  int l15 = lane & 15, l4 = lane >> 4;
  int jt = wave;
  f32x4 acc;
  {
    float bv = bias[jt*16 + l15];
    acc[0]=bv; acc[1]=bv; acc[2]=bv; acc[3]=bv;
  }
  #pragma unroll
  for (int ks = 0; ks < 8; ++ks){
    bf16x8 af = *(const bf16x8*)&Albuf[l15][ks*32 + l4*8];
    bf16x8 bf = *(const bf16x8*)&Wfrag[(size_t)(((jt*8 + ks)*64) + lane) * 8];
    acc = __builtin_amdgcn_mfma_f32_16x16x32_bf16(af, bf, acc, 0, 0, 0);
  }
  {
    int col = jt*16 + l15;
    #pragma unroll
    for (int i = 0; i < 4; ++i)
      gbuf[l4*4 + i][col] = acc[i];
  }
  __syncthreads();

  if (n < N){
    int r = wave;
    float gi = gbuf[r][lane], gf = gbuf[r][64+lane], gg2 = gbuf[r][128+lane], go = gbuf[r][192+lane];
    float cn = sigmoidf_(gf)*c[(size_t)n*HH+lane] + sigmoidf_(gi)*tanhf(gg2);
    float hnv = sigmoidf_(go)*tanhf(cn);
    c[(size_t)n*HH+lane] = cn;
    unsigned short hb = f2bf(hnv);
    h_next[(size_t)n*HH+lane] = hb;
    if (h2_store) h2_store[(size_t)n*HH+lane] = hb;
  }
}

// ================= output head (bf16 inputs; xrb node-major) =================
__global__ void out_gemm(const unsigned short* __restrict__ xrb, const unsigned short* __restrict__ h2s,
                         const float* __restrict__ Wout, const float* __restrict__ bout,
                         float* __restrict__ out, int N){
  int idx = blockIdx.x*blockDim.x + threadIdx.x;
  if (idx >= NF*N*OO) return;
  int o = idx & (OO-1);
  int row = idx >> 3;                     // tt*N + n
  int tt = row / N, n = row % N;
  const unsigned short* xv = xrb + ((size_t)n*TT + (TT-NF) + tt)*HH;
  const unsigned short* hv = h2s + (size_t)row*HH;
  float acc = bout[o];
  #pragma unroll
  for (int k = 0; k < HH; ++k)
    acc += bf2f(xv[k])*Wout[k*OO+o] + bf2f(hv[k])*Wout[(HH+k)*OO+o];
  out[idx] = acc;
}

__global__ void copyk(const float* __restrict__ s, float* __restrict__ d, int n){
  int i = blockIdx.x*blockDim.x + threadIdx.x;
  if (i < n) d[i] = s[i];
}

extern "C" void kernel_launch(void* const* d_in, const int* in_sizes, int n_in,
                              void* d_out, int out_size, void* d_ws, size_t ws_size,
                              hipStream_t stream){
  const float* x      = (const float*)d_in[0];
  const int*   ei     = (const int*)  d_in[1];
  const float* ew     = (const float*)d_in[2];
  const float* sWr    = (const float*)d_in[3];
  const float* sWroot = (const float*)d_in[4];
  const float* sb     = (const float*)d_in[5];
  const float* l1Wr   = (const float*)d_in[6];
  const float* l1Wroot= (const float*)d_in[7];
  const float* l1b    = (const float*)d_in[8];
  const float* l2Wr   = (const float*)d_in[9];
  const float* l2Wroot= (const float*)d_in[10];
  const float* l2b    = (const float*)d_in[11];
  const float* Wout   = (const float*)d_in[12];
  const float* bout   = (const float*)d_in[13];

  const int E = in_sizes[2];
  const int N = in_sizes[0] / (TT*FF);
  const int* src = ei;
  const int* dst = ei + E;

  float* out0   = (float*)d_out;              // [4,N,8]
  float* c2out  = out0 + (size_t)NF*N*OO;     // [N,64]
  float* embout = c2out + (size_t)N*HH;       // [12,N,64]

  float* w = (float*)d_ws;
  float* cbuf   = w;  w += (size_t)N*HH;
  float* invd   = w;  w += N;
  int*   cnt    = (int*)w;  w += N;
  int*   fill   = (int*)w;  w += N;
  int*   loc    = (int*)w;  w += N;
  int*   btot   = (int*)w;  w += 64;
  int*   boff   = (int*)w;  w += 64;
  int*   ptr    = (int*)w;  w += (N+2);       // keep int2 array 8B-aligned
  int2*  csr_sw = (int2*)w; w += (size_t)2*E;
  unsigned short* Wf1 = (unsigned short*)w; w += (size_t)16*8*64*8/2;
  unsigned short* Wf2 = (unsigned short*)w; w += (size_t)16*8*64*8/2;
  unsigned short* Sfg = (unsigned short*)w; w += (size_t)4*2*64*8/2;
  unsigned short* xb     = (unsigned short*)w; w += (size_t)TT*N*FF/2;
  unsigned short* aggb   = (unsigned short*)w; w += (size_t)TT*N*FF/2;
  unsigned short* xrb    = (unsigned short*)w; w += (size_t)TT*N*HH/2;
  unsigned short* xraggb = (unsigned short*)w; w += (size_t)TT*N*HH/2;
  unsigned short* hA     = (unsigned short*)w; w += (size_t)N*HH/2;
  unsigned short* hB     = (unsigned short*)w; w += (size_t)N*HH/2;
  unsigned short* h2s    = (unsigned short*)w; w += (size_t)NF*N*HH/2;

  hipMemsetAsync(cnt,  0, (size_t)N*4, stream);
  hipMemsetAsync(fill, 0, (size_t)N*4, stream);
  hipMemsetAsync(cbuf, 0, (size_t)N*HH*4, stream);  // c0 (h0 handled via skip_h)

  const int nb = (N + 1023) / 1024;          // 20 for N=20000 (<=64)
  hist_kernel<<<(E+255)/256, 256, 0, stream>>>(dst, cnt, E);
  scan_local<<<nb, 1024, 0, stream>>>(cnt, loc, btot, N);
  scan_tot<<<1, 64, 0, stream>>>(btot, boff, nb, ptr + N);
  scan_fix<<<nb, 1024, 0, stream>>>(loc, boff, cnt, ptr, invd, N);
  fill_kernel<<<(E+255)/256, 256, 0, stream>>>(src, dst, ew, ptr, fill, csr_sw, E);

  pack_wfrag<<<(16*8*64*8+255)/256, 256, 0, stream>>>(l1Wr, l1Wroot, Wf1);
  pack_wfrag<<<(16*8*64*8+255)/256, 256, 0, stream>>>(l2Wr, l2Wroot, Wf2);
  pack_sfrag<<<(4*2*64*8+255)/256, 256, 0, stream>>>(sWr, sWroot, Sfg);
  xpose_conv<<<((size_t)TT*N*FF+255)/256, 256, 0, stream>>>(x, xb, N);

  sage_gather<<<(N+3)/4, 256, 0, stream>>>(xb, ptr, csr_sw, invd, aggb, N);
  {
    int Mrows = TT*N;
    sage_mfma<<<(Mrows+63)/64, 256, 0, stream>>>(aggb, xb, Sfg, sb, embout, xrb, N, Mrows);
  }
  xr_gather<<<(N+3)/4, 256, 0, stream>>>(xrb, ptr, csr_sw, invd, xraggb, N);

  const int sBlocks = (N + BR - 1) / BR;   // 1250
  unsigned short* hp = hA; unsigned short* hn = hB;
  // LSTM1 (step 0: h=0 -> skip gather)
  for (int t = 0; t < TT; ++t){
    lstm_mfma<<<sBlocks, 1024, 0, stream>>>(xrb + (size_t)t*HH, xraggb + (size_t)t*HH,
                                            hp, hn, cbuf, invd, ptr, csr_sw,
                                            Wf1, l1b, nullptr, N, t == 0 ? 1 : 0);
    unsigned short* tmp = hp; hp = hn; hn = tmp;
  }
  // LSTM2 (continues from h1[-1], c1); h2 stored for t>=8
  for (int t = 0; t < TT; ++t){
    unsigned short* store = (t >= TT-NF) ? (h2s + (size_t)(t-(TT-NF))*N*HH) : nullptr;
    lstm_mfma<<<sBlocks, 1024, 0, stream>>>(xrb + (size_t)t*HH, xraggb + (size_t)t*HH,
                                            hp, hn, cbuf, invd, ptr, csr_sw,
                                            Wf2, l2b, store, N, 0);
    unsigned short* tmp = hp; hp = hn; hn = tmp;
  }

  out_gemm<<<((size_t)NF*N*OO+255)/256, 256, 0, stream>>>(xrb, h2s,
                                                          Wout, bout, out0, N);
  copyk<<<((size_t)N*HH+255)/256, 256, 0, stream>>>(cbuf, c2out, N*HH);
}